// Round 3
// baseline (1408.784 us; speedup 1.0000x reference)
//
#include <hip/hip_runtime.h>
#include <hip/hip_bf16.h>

typedef __attribute__((ext_vector_type(8))) short short8;
typedef __attribute__((ext_vector_type(4))) float f32x4;

#define MFMA16(a,b,c) __builtin_amdgcn_mfma_f32_16x16x32_bf16((a),(b),(c),0,0,0)

__device__ __forceinline__ short f2b(float f){
    return __builtin_bit_cast(short, __float2bfloat16(f));
}
__device__ __forceinline__ void split2(float f, short &hi, short &lo){
    __hip_bfloat16 h = __float2bfloat16(f);
    hi = __builtin_bit_cast(short, h);
    lo = f2b(f - __bfloat162float(h));
}
// async global->LDS 16B: dest = wave-uniform base + lane*16
__device__ __forceinline__ void cp16(void* l, const void* g){
    __builtin_amdgcn_global_load_lds(
        (const __attribute__((address_space(1))) unsigned int*)g,
        (__attribute__((address_space(3))) unsigned int*)l, 16, 0, 0);
}

// ---------------- cast + transpose: f32 [R][C] -> bf16 hi/lo [C][R], 64x64 tiles --
__global__ __launch_bounds__(256)
void castT_k(const float* __restrict__ in, short* __restrict__ hiT,
             short* __restrict__ loT, int R, int C)
{
    __shared__ float t[64][65];
    size_t boff = (size_t)blockIdx.z * (size_t)R * (size_t)C;
    int r0 = blockIdx.y * 64, c0 = blockIdx.x * 64;
    int tid = threadIdx.x;
    int lr = tid >> 4, lc = (tid & 15) * 4;
#pragma unroll
    for (int p = 0; p < 4; p++) {
        int r = p*16 + lr;
        float4 v = *reinterpret_cast<const float4*>(in + boff + (size_t)(r0+r)*C + c0 + lc);
        t[r][lc] = v.x; t[r][lc+1] = v.y; t[r][lc+2] = v.z; t[r][lc+3] = v.w;
    }
    __syncthreads();
#pragma unroll
    for (int p = 0; p < 2; p++) {
        int ch = p*256 + tid;
        int c = ch >> 3, seg = (ch & 7) * 8;
        short8 hv, lv;
#pragma unroll
        for (int i = 0; i < 8; i++) {
            float v = t[seg+i][c];
            short h, l; split2(v, h, l);
            hv[i] = h; lv[i] = l;
        }
        size_t o = boff + (size_t)(c0+c)*R + r0 + seg;
        *reinterpret_cast<short8*>(hiT + o) = hv;
        if (loT) *reinterpret_cast<short8*>(loT + o) = lv;
    }
}

// ---------------- LayerNorm: f32 [rows][1024] -> bf16 hi (+optional lo) ----------
__global__ __launch_bounds__(256)
void ln_k(const float* __restrict__ x, const float* __restrict__ g,
          const float* __restrict__ be, short* __restrict__ outhi,
          short* __restrict__ outlo)
{
    int row = blockIdx.x;
    const float* xr = x + (size_t)row * 1024;
    int tid = threadIdx.x;
    float4 v = reinterpret_cast<const float4*>(xr)[tid];
    float s = v.x + v.y + v.z + v.w;
    float q = v.x*v.x + v.y*v.y + v.z*v.z + v.w*v.w;
#pragma unroll
    for (int m = 1; m < 64; m <<= 1) { s += __shfl_xor(s, m); q += __shfl_xor(q, m); }
    __shared__ float ss[4], sq[4];
    int wid = tid >> 6;
    if ((tid & 63) == 0) { ss[wid] = s; sq[wid] = q; }
    __syncthreads();
    float S = ss[0] + ss[1] + ss[2] + ss[3];
    float Qs = sq[0] + sq[1] + sq[2] + sq[3];
    float mean = S * (1.f/1024.f);
    float var = Qs * (1.f/1024.f) - mean*mean;
    float rstd = rsqrtf(var + 1e-5f);
    float4 gv = reinterpret_cast<const float4*>(g)[tid];
    float4 bv = reinterpret_cast<const float4*>(be)[tid];
    float o[4];
    o[0] = (v.x-mean)*rstd*gv.x + bv.x;
    o[1] = (v.y-mean)*rstd*gv.y + bv.y;
    o[2] = (v.z-mean)*rstd*gv.z + bv.z;
    o[3] = (v.w-mean)*rstd*gv.w + bv.w;
    short hs[4], ls[4];
#pragma unroll
    for (int i = 0; i < 4; i++) split2(o[i], hs[i], ls[i]);
    typedef __attribute__((ext_vector_type(4))) short short4v;
    short4v hv; hv[0]=hs[0]; hv[1]=hs[1]; hv[2]=hs[2]; hv[3]=hs[3];
    *reinterpret_cast<short4v*>(outhi + (size_t)row*1024 + tid*4) = hv;
    if (outlo) {
        short4v lv; lv[0]=ls[0]; lv[1]=ls[1]; lv[2]=ls[2]; lv[3]=ls[3];
        *reinterpret_cast<short4v*>(outlo + (size_t)row*1024 + tid*4) = lv;
    }
}

// ---------------- cap projection: text_state[B,1024] @ cap_w[1024,1024] + cap_b ----
__global__ __launch_bounds__(256)
void cap_k(const float* __restrict__ ts, const float* __restrict__ cw,
           const float* __restrict__ cb, float* __restrict__ capo)
{
    int b = blockIdx.y;
    int d = blockIdx.x * 64 + (threadIdx.x & 63);
    int ks = threadIdx.x >> 6;
    const float* t = ts + (size_t)b * 1024;
    float acc = 0.f;
    for (int k = ks*256; k < ks*256 + 256; k++)
        acc = fmaf(t[k], cw[(size_t)k*1024 + d], acc);
    __shared__ float red[4][64];
    red[ks][threadIdx.x & 63] = acc;
    __syncthreads();
    if (ks == 0)
        capo[(size_t)b*1024 + d] = red[0][threadIdx.x&63] + red[1][threadIdx.x&63]
                                 + red[2][threadIdx.x&63] + red[3][threadIdx.x&63] + cb[d];
}

// ---------------- gate: inline f32 LN2 + logits, top-2, softmax weights, lists ----
__global__ __launch_bounds__(64)
void gate_k(const float* __restrict__ x2, const float* __restrict__ g,
            const float* __restrict__ be, const float* __restrict__ capo,
            const float* __restrict__ gw, const float* __restrict__ gb,
            int* __restrict__ elist, float* __restrict__ ewt, int* __restrict__ cnt)
{
    int t = blockIdx.x;
    int b = t >> 10;
    int lane = threadIdx.x;
    const float* xr = x2 + (size_t)t * 1024;
    float v[16];
    float s = 0.f, q = 0.f;
#pragma unroll
    for (int i = 0; i < 16; i++) {
        v[i] = xr[i*64 + lane];
        s += v[i]; q += v[i]*v[i];
    }
#pragma unroll
    for (int m = 1; m < 64; m <<= 1) { s += __shfl_xor(s, m); q += __shfl_xor(q, m); }
    float mean = s * (1.f/1024.f);
    float var = q * (1.f/1024.f) - mean*mean;
    float rstd = rsqrtf(var + 1e-5f);
    float acc[8] = {0,0,0,0,0,0,0,0};
    const float* cr = capo + (size_t)b * 1024;
#pragma unroll
    for (int i = 0; i < 16; i++) {
        int d = i*64 + lane;
        float gi = (v[i]-mean)*rstd*g[d] + be[d] + cr[d];
        const float4* gp = reinterpret_cast<const float4*>(gw + (size_t)d*8);
        float4 g0 = gp[0], g1 = gp[1];
        acc[0] += gi*g0.x; acc[1] += gi*g0.y; acc[2] += gi*g0.z; acc[3] += gi*g0.w;
        acc[4] += gi*g1.x; acc[5] += gi*g1.y; acc[6] += gi*g1.z; acc[7] += gi*g1.w;
    }
#pragma unroll
    for (int e = 0; e < 8; e++)
#pragma unroll
        for (int m = 1; m < 64; m <<= 1) acc[e] += __shfl_xor(acc[e], m);
    if (lane == 0) {
        float v0 = -1e30f, v1 = -1e30f; int i0 = 0, i1 = 0;
#pragma unroll
        for (int e = 0; e < 8; e++) {
            float lg = acc[e] + gb[e];
            if (lg > v0) { v1 = v0; i1 = i0; v0 = lg; i0 = e; }
            else if (lg > v1) { v1 = lg; i1 = e; }
        }
        float w0 = 1.f / (1.f + __expf(v1 - v0));
        float w1 = 1.f - w0;
        int p0 = atomicAdd(&cnt[i0], 1);
        elist[i0*4096 + p0] = t; ewt[i0*4096 + p0] = w0;
        int p1 = atomicAdd(&cnt[i1], 1);
        elist[i1*4096 + p1] = t; ewt[i1*4096 + p1] = w1;
    }
}

// ---------------- scan: expert bases + load output ----------
__global__ void scan_k(const int* __restrict__ cnt, int* __restrict__ ebase,
                       float* __restrict__ outload)
{
    int t = threadIdx.x;
    if (t == 0) { int s = 0; for (int e = 0; e < 8; e++) { ebase[e] = s; s += cnt[e]; } }
    if (t < 8) outload[t] = (float)cnt[t] * (1.f/8192.f);
}

// ---------------- GEMM: C = A[M,K] @ Bt[N,K]^T; async LDS pipeline, XOR swizzle ----
// SP = split-bf16 3-term (hh + hl + lh). Tiles 128x128, BK=32.
enum { M_QKV = 0, M_WO = 1, M_F1 = 2, M_F2 = 3 };

template<int MODE, bool SP>
__global__ __launch_bounds__(256)
void gemm_k(const short* __restrict__ Ahi, const short* __restrict__ Alo,
            const short* __restrict__ Bhi, const short* __restrict__ Blo,
            const float* __restrict__ bias,
            float* __restrict__ outf, short* __restrict__ outhi,
            const float* __restrict__ resid,
            const int* __restrict__ elist, const float* __restrict__ ew,
            const int* __restrict__ cnt, const int* __restrict__ ebase,
            int M, int N, int K)
{
    constexpr int NT = SP ? 4 : 2;       // tiles per K-step (Ahi[,Alo],Bhi[,Blo])
    constexpr bool MOE = (MODE == M_F1 || MODE == M_F2);
    int e = blockIdx.z;
    int m0 = blockIdx.y * 128, n0 = blockIdx.x * 128;
    int Mloc = M;
    int baseE = 0;
    if (MOE) {
        Mloc = cnt[e];
        if (m0 >= Mloc) return;
        baseE = ebase[e];
        Bhi += (size_t)e * 4194304;      // N*K == 4096*1024 for both FFN gemms
        bias += (size_t)e * N;
    }
    __shared__ short lds[NT * 8192];     // 2 bufs x NT tiles x 4096 shorts (8KB/tile)
    int* rowmap = nullptr;
    if constexpr (MOE) {
        __shared__ int rowmap_s[128];
        rowmap = rowmap_s;
    }
    int tid = threadIdx.x;
    int lane = tid & 63, wid = tid >> 6;
    int wr = wid >> 1, wc = wid & 1;
    int rl = lane & 15, rg = lane >> 4;

    if constexpr (MOE) {
        if (tid < 128) {
            int mrow = m0 + tid;
            int ar;
            if (MODE == M_F1) {
                int idx = mrow < Mloc ? mrow : Mloc - 1;
                ar = elist[e*4096 + idx];
            } else {
                ar = baseE + mrow;
                if (ar > 8191) ar = 8191;
            }
            rowmap[tid] = ar;
        }
        __syncthreads();
    }

    // stage one K-step (NT tiles) into buffer `buf`; swizzled source chunks
    auto STAGE = [&](int buf, int k0) {
        short* base = lds + buf * (NT * 4096);
        for (int is = wid; is < NT * 8; is += 4) {
            int tile = is >> 3, issue = is & 7;
            int row = issue*16 + (lane >> 2);
            int sch = (lane & 3) ^ ((row >> 1) & 3);
            const short* src;
            if (tile < (SP ? 2 : 1)) {
                int ar = MOE ? rowmap[row] : (m0 + row);
                const short* Ab = (SP && tile == 1) ? Alo : Ahi;
                src = Ab + (size_t)ar * K + k0 + sch*8;
            } else {
                const short* Bb = (SP && tile == 3) ? Blo : Bhi;
                src = Bb + (size_t)(n0 + row) * K + k0 + sch*8;
            }
            cp16(base + tile*4096 + issue*512, src);
        }
    };

    f32x4 acc[4][4] = {};
    int nt = K >> 5;
    STAGE(0, 0);
    int cur = 0;
    for (int t = 0; t < nt; ++t) {
        __syncthreads();                          // drains vmcnt: buf[cur] ready
        if (t + 1 < nt) STAGE(cur ^ 1, (t + 1) * 32);
        const short* cb = lds + cur * (NT * 4096);
        short8 afh[4], bfh[4], afl[4], bfl[4];
#pragma unroll
        for (int i = 0; i < 4; i++) {
            int ra = wr*64 + i*16 + rl;
            int ca = ra*32 + ((rg ^ ((ra >> 1) & 3)) * 8);
            afh[i] = *reinterpret_cast<const short8*>(cb + ca);
            if (SP) afl[i] = *reinterpret_cast<const short8*>(cb + 4096 + ca);
            int rb = wc*64 + i*16 + rl;
            int cb2 = rb*32 + ((rg ^ ((rb >> 1) & 3)) * 8);
            bfh[i] = *reinterpret_cast<const short8*>(cb + (SP?2:1)*4096 + cb2);
            if (SP) bfl[i] = *reinterpret_cast<const short8*>(cb + 3*4096 + cb2);
        }
#pragma unroll
        for (int mi = 0; mi < 4; mi++)
#pragma unroll
            for (int ni = 0; ni < 4; ni++) {
                acc[mi][ni] = MFMA16(afh[mi], bfh[ni], acc[mi][ni]);
                if (SP) {
                    acc[mi][ni] = MFMA16(afh[mi], bfl[ni], acc[mi][ni]);
                    acc[mi][ni] = MFMA16(afl[mi], bfh[ni], acc[mi][ni]);
                }
            }
        cur ^= 1;
    }
#pragma unroll
    for (int mi = 0; mi < 4; mi++) {
#pragma unroll
        for (int ni = 0; ni < 4; ni++) {
            int col = n0 + wc*64 + ni*16 + rl;
            f32x4 a = acc[mi][ni];
#pragma unroll
            for (int r = 0; r < 4; r++) {
                int mrow = m0 + wr*64 + mi*16 + rg*4 + r;
                if (mrow >= Mloc) continue;
                float val = a[r] + bias[col];
                if (MODE == M_QKV) {
                    int which = col >> 10, d = col & 1023;
                    int hh = d >> 6, hd = d & 63;
                    int bb = mrow >> 10, sidx = mrow & 1023;
                    size_t o = (size_t)which*4194304 + (((size_t)(bb*16 + hh))*1024 + sidx)*64 + hd;
                    short h, l; split2(val, h, l);
                    outhi[o] = h; outhi[12582912 + o] = l;
                } else if (MODE == M_WO) {
                    size_t o = (size_t)mrow*1024 + col;
                    outf[o] = val + resid[o];
                } else if (MODE == M_F1) {
                    float xx = val;
                    float z = 0.7978845608028654f * (xx + 0.044715f*xx*xx*xx);
                    float th = 1.f - 2.f/(1.f + __expf(2.f*z));
                    float gl = 0.5f*xx*(1.f + th);
                    outhi[(size_t)(baseE + mrow)*4096 + col] = f2b(gl);
                } else { // M_F2
                    int tok = elist[e*4096 + mrow];
                    float w = ew[e*4096 + mrow];
                    atomicAdd(&outf[(size_t)tok*1024 + col], w*val);
                }
            }
        }
    }
}

// ---------------- fused flash attention, split-bf16 (6-term QK, 3-term PV) ----
// grid: (qt=16, bh=64); block 256 (4 waves, 16 q-rows each); KV tiles of 64
__global__ __launch_bounds__(256)
void attn_k(const short* __restrict__ qkvhi, const short* __restrict__ qkvlo,
            const float* __restrict__ relb,
            short* __restrict__ obhi, short* __restrict__ oblo)
{
    int bh = blockIdx.y, qt = blockIdx.x;
    int b = bh >> 4, h = bh & 15;
    int tid = threadIdx.x, wid = tid >> 6, lane = tid & 63;
    int rl = lane & 15, rg = lane >> 4;
    const short* Qh = qkvhi + (size_t)bh * 65536;
    const short* Ql = qkvlo + (size_t)bh * 65536;
    const short* Kh_g = qkvhi + 4194304 + (size_t)bh * 65536;
    const short* Kl_g = qkvlo + 4194304 + (size_t)bh * 65536;
    const short* Vh_g = qkvhi + 8388608 + (size_t)bh * 65536;
    const short* Vl_g = qkvlo + 8388608 + (size_t)bh * 65536;
    __shared__ short Kh[64][72], Kl[64][72];
    __shared__ short Vh[64][72], Vl[64][72];
    __shared__ short Ph[4][16][72], Pl[4][16][72];
    int q0 = qt*64 + wid*16;
    short8 qh0 = *reinterpret_cast<const short8*>(Qh + (size_t)(q0+rl)*64 + rg*8);
    short8 qh1 = *reinterpret_cast<const short8*>(Qh + (size_t)(q0+rl)*64 + 32 + rg*8);
    short8 ql0 = *reinterpret_cast<const short8*>(Ql + (size_t)(q0+rl)*64 + rg*8);
    short8 ql1 = *reinterpret_cast<const short8*>(Ql + (size_t)(q0+rl)*64 + 32 + rg*8);
    f32x4 O[4] = {};
    float mr[4] = {-1e30f,-1e30f,-1e30f,-1e30f};
    float lr[4] = {0.f,0.f,0.f,0.f};
    const float* rb = relb + h*2047 + 1023;
    for (int kt = 0; kt < 16; ++kt) {
        int kb0 = kt * 64;
        __syncthreads();
#pragma unroll
        for (int j = 0; j < 2; j++) {
            int idx = j*256 + tid;
            int row = idx >> 3, cb = (idx & 7) * 8;
            *reinterpret_cast<short8*>(&Kh[row][cb]) =
                *reinterpret_cast<const short8*>(Kh_g + (size_t)(kb0+row)*64 + cb);
            *reinterpret_cast<short8*>(&Kl[row][cb]) =
                *reinterpret_cast<const short8*>(Kl_g + (size_t)(kb0+row)*64 + cb);
            short8 vh = *reinterpret_cast<const short8*>(Vh_g + (size_t)(kb0+row)*64 + cb);
            short8 vl = *reinterpret_cast<const short8*>(Vl_g + (size_t)(kb0+row)*64 + cb);
#pragma unroll
            for (int i = 0; i < 8; i++) { Vh[cb+i][row] = vh[i]; Vl[cb+i][row] = vl[i]; }
        }
        __syncthreads();
        f32x4 sc[4];
#pragma unroll
        for (int c = 0; c < 4; c++) {
            short8 kh0 = *reinterpret_cast<short8*>(&Kh[c*16+rl][rg*8]);
            short8 kh1 = *reinterpret_cast<short8*>(&Kh[c*16+rl][32+rg*8]);
            short8 kl0 = *reinterpret_cast<short8*>(&Kl[c*16+rl][rg*8]);
            short8 kl1 = *reinterpret_cast<short8*>(&Kl[c*16+rl][32+rg*8]);
            f32x4 t = {};
            t = MFMA16(qh0, kh0, t); t = MFMA16(qh1, kh1, t);
            t = MFMA16(qh0, kl0, t); t = MFMA16(qh1, kl1, t);
            t = MFMA16(ql0, kh0, t); t = MFMA16(ql1, kh1, t);
            sc[c] = t;
        }
        float pm[4] = {-1e30f,-1e30f,-1e30f,-1e30f};
#pragma unroll
        for (int c = 0; c < 4; c++) {
            int kk = kb0 + c*16 + rl;
#pragma unroll
            for (int r = 0; r < 4; r++) {
                int q = q0 + rg*4 + r;
                float sv = sc[c][r]*0.125f + rb[q - kk];
                sc[c][r] = sv;
                pm[r] = fmaxf(pm[r], sv);
            }
        }
#pragma unroll
        for (int r = 0; r < 4; r++) {
            pm[r] = fmaxf(pm[r], __shfl_xor(pm[r], 1));
            pm[r] = fmaxf(pm[r], __shfl_xor(pm[r], 2));
            pm[r] = fmaxf(pm[r], __shfl_xor(pm[r], 4));
            pm[r] = fmaxf(pm[r], __shfl_xor(pm[r], 8));
        }
        float scl[4], ps[4];
#pragma unroll
        for (int r = 0; r < 4; r++) {
            float mn = fmaxf(mr[r], pm[r]);
            scl[r] = __expf(mr[r] - mn);
            mr[r] = mn;
            ps[r] = 0.f;
        }
#pragma unroll
        for (int c = 0; c < 4; c++)
#pragma unroll
            for (int r = 0; r < 4; r++) {
                float p = __expf(sc[c][r] - mr[r]);
                sc[c][r] = p;
                ps[r] += p;
            }
#pragma unroll
        for (int r = 0; r < 4; r++) {
            ps[r] += __shfl_xor(ps[r], 1);
            ps[r] += __shfl_xor(ps[r], 2);
            ps[r] += __shfl_xor(ps[r], 4);
            ps[r] += __shfl_xor(ps[r], 8);
            lr[r] = lr[r]*scl[r] + ps[r];
        }
#pragma unroll
        for (int cc = 0; cc < 4; cc++) {
            O[cc][0] *= scl[0]; O[cc][1] *= scl[1];
            O[cc][2] *= scl[2]; O[cc][3] *= scl[3];
        }
#pragma unroll
        for (int c = 0; c < 4; c++)
#pragma unroll
            for (int r = 0; r < 4; r++) {
                short hp, lp; split2(sc[c][r], hp, lp);
                Ph[wid][rg*4+r][c*16+rl] = hp;
                Pl[wid][rg*4+r][c*16+rl] = lp;
            }
#pragma unroll
        for (int cc = 0; cc < 4; cc++) {
#pragma unroll
            for (int ks = 0; ks < 2; ks++) {
                short8 ph = *reinterpret_cast<short8*>(&Ph[wid][rl][ks*32 + rg*8]);
                short8 pl = *reinterpret_cast<short8*>(&Pl[wid][rl][ks*32 + rg*8]);
                short8 vh = *reinterpret_cast<short8*>(&Vh[cc*16+rl][ks*32 + rg*8]);
                short8 vl = *reinterpret_cast<short8*>(&Vl[cc*16+rl][ks*32 + rg*8]);
                O[cc] = MFMA16(ph, vh, O[cc]);
                O[cc] = MFMA16(ph, vl, O[cc]);
                O[cc] = MFMA16(pl, vh, O[cc]);
            }
        }
    }
#pragma unroll
    for (int cc = 0; cc < 4; cc++) {
#pragma unroll
        for (int r = 0; r < 4; r++) {
            int q = q0 + rg*4 + r;
            float val = O[cc][r] / lr[r];
            size_t o = ((size_t)(b*1024 + q))*1024 + h*64 + cc*16 + rl;
            short hv, lv; split2(val, hv, lv);
            obhi[o] = hv; oblo[o] = lv;
        }
    }
}

// ---------------------------------------------------------------------------
extern "C" void kernel_launch(void* const* d_in, const int* in_sizes, int n_in,
                              void* d_out, int out_size, void* d_ws, size_t ws_size,
                              hipStream_t stream)
{
    const float* x     = (const float*)d_in[0];
    const float* ts    = (const float*)d_in[1];
    const float* ln1g  = (const float*)d_in[2];
    const float* ln1b_ = (const float*)d_in[3];
    const float* wqkv  = (const float*)d_in[4];
    const float* bqkv  = (const float*)d_in[5];
    const float* wo    = (const float*)d_in[6];
    const float* bo    = (const float*)d_in[7];
    const float* relb  = (const float*)d_in[8];
    const float* ln2g  = (const float*)d_in[9];
    const float* ln2b_ = (const float*)d_in[10];
    const float* capw  = (const float*)d_in[11];
    const float* capb  = (const float*)d_in[12];
    const float* gatew = (const float*)d_in[13];
    const float* gateb = (const float*)d_in[14];
    const float* w1    = (const float*)d_in[15];
    const float* b1    = (const float*)d_in[16];
    const float* w2    = (const float*)d_in[17];
    const float* b2    = (const float*)d_in[18];
    float* out = (float*)d_out;

    char* p = (char*)d_ws;
    short* w1T    = (short*)p; p += 67108864;
    short* w2T    = (short*)p; p += 67108864;
    short* wqThi  = (short*)p; p += 6291456;
    short* wqTlo  = (short*)p; p += 6291456;
    short* woThi  = (short*)p; p += 2097152;
    short* woTlo  = (short*)p; p += 2097152;
    short* qkvhi  = (short*)p; p += 25165824;   // qkvlo = qkvhi + 12582912 (contiguous)
    short* qkvlo  = qkvhi + 12582912; p += 0;
    p += 25165824 - 25165824;                    // (qkvhi block already 2x12M)
    p = (char*)(qkvhi + 25165824);
    short* h2b    = (short*)p; p += 8388608;
    float* capo   = (float*)p; p += 16384;
    int*   elist  = (int*)p;   p += 131072;
    float* ewt    = (float*)p; p += 131072;
    int*   cnt    = (int*)p;   p += 256;
    int*   ebase  = (int*)p;   p += 256;
    short* mid    = (short*)p; p += 67108864;   // 8192x4096 bf16; front aliased below
    short* h1hi   = mid;                        // live: ln1 -> QKV gemm
    short* h1lo   = mid + 4194304;
    short* obhi   = mid + 8388608;              // live: attn -> WO gemm
    short* oblo   = mid + 12582912;

    hipMemsetAsync(cnt, 0, 32, stream);

    castT_k<<<dim3(48, 16, 1), 256, 0, stream>>>(wqkv, wqThi, wqTlo, 1024, 3072);
    castT_k<<<dim3(16, 16, 1), 256, 0, stream>>>(wo,   woThi, woTlo, 1024, 1024);
    castT_k<<<dim3(64, 16, 8), 256, 0, stream>>>(w1,   w1T,  nullptr, 1024, 4096);
    castT_k<<<dim3(16, 64, 8), 256, 0, stream>>>(w2,   w2T,  nullptr, 4096, 1024);

    ln_k<<<4096, 256, 0, stream>>>(x, ln1g, ln1b_, h1hi, h1lo);

    gemm_k<M_QKV, true><<<dim3(24, 32, 1), 256, 0, stream>>>(
        h1hi, h1lo, wqThi, wqTlo, bqkv, nullptr, qkvhi,
        nullptr, nullptr, nullptr, nullptr, nullptr, 4096, 3072, 1024);

    attn_k<<<dim3(16, 64), 256, 0, stream>>>(qkvhi, qkvlo, relb, obhi, oblo);

    gemm_k<M_WO, true><<<dim3(8, 32, 1), 256, 0, stream>>>(
        obhi, oblo, woThi, woTlo, bo, out, nullptr,
        x, nullptr, nullptr, nullptr, nullptr, 4096, 1024, 1024);

    cap_k<<<dim3(16, 4), 256, 0, stream>>>(ts, capw, capb, capo);

    ln_k<<<4096, 256, 0, stream>>>(out, ln2g, ln2b_, h2b, nullptr);

    gate_k<<<4096, 64, 0, stream>>>(out, ln2g, ln2b_, capo, gatew, gateb,
                                    elist, ewt, cnt);

    scan_k<<<1, 64, 0, stream>>>(cnt, ebase, out + 4194304);

    gemm_k<M_F1, false><<<dim3(32, 32, 8), 256, 0, stream>>>(
        h2b, nullptr, w1T, nullptr, b1, nullptr, mid,
        nullptr, elist, ewt, cnt, ebase, 4096, 4096, 1024);

    gemm_k<M_F2, false><<<dim3(8, 32, 8), 256, 0, stream>>>(
        mid, nullptr, w2T, nullptr, b2, out, nullptr,
        nullptr, elist, ewt, cnt, ebase, 4096, 1024, 4096);

    (void)in_sizes; (void)n_in; (void)out_size; (void)ws_size;
}

// Round 4
// 1127.639 us; speedup vs baseline: 1.2493x; 1.2493x over previous
//
#include <hip/hip_runtime.h>
#include <hip/hip_bf16.h>

typedef __attribute__((ext_vector_type(8))) short short8;
typedef __attribute__((ext_vector_type(4))) float f32x4;

#define MFMA16(a,b,c) __builtin_amdgcn_mfma_f32_16x16x32_bf16((a),(b),(c),0,0,0)

__device__ __forceinline__ short f2b(float f){
    return __builtin_bit_cast(short, __float2bfloat16(f));
}
__device__ __forceinline__ void split2(float f, short &hi, short &lo){
    __hip_bfloat16 h = __float2bfloat16(f);
    hi = __builtin_bit_cast(short, h);
    lo = f2b(f - __bfloat162float(h));
}
// async global->LDS 16B: dest = wave-uniform base + lane*16
__device__ __forceinline__ void cp16(void* l, const void* g){
    __builtin_amdgcn_global_load_lds(
        (const __attribute__((address_space(1))) unsigned int*)g,
        (__attribute__((address_space(3))) unsigned int*)l, 16, 0, 0);
}

// ---------------- cast + transpose: f32 [R][C] -> bf16 hi/lo [C][R], 64x64 tiles --
__global__ __launch_bounds__(256)
void castT_k(const float* __restrict__ in, short* __restrict__ hiT,
             short* __restrict__ loT, int R, int C)
{
    __shared__ float t[64][65];
    size_t boff = (size_t)blockIdx.z * (size_t)R * (size_t)C;
    int r0 = blockIdx.y * 64, c0 = blockIdx.x * 64;
    int tid = threadIdx.x;
    int lr = tid >> 4, lc = (tid & 15) * 4;
#pragma unroll
    for (int p = 0; p < 4; p++) {
        int r = p*16 + lr;
        float4 v = *reinterpret_cast<const float4*>(in + boff + (size_t)(r0+r)*C + c0 + lc);
        t[r][lc] = v.x; t[r][lc+1] = v.y; t[r][lc+2] = v.z; t[r][lc+3] = v.w;
    }
    __syncthreads();
#pragma unroll
    for (int p = 0; p < 2; p++) {
        int ch = p*256 + tid;
        int c = ch >> 3, seg = (ch & 7) * 8;
        short8 hv, lv;
#pragma unroll
        for (int i = 0; i < 8; i++) {
            float v = t[seg+i][c];
            short h, l; split2(v, h, l);
            hv[i] = h; lv[i] = l;
        }
        size_t o = boff + (size_t)(c0+c)*R + r0 + seg;
        *reinterpret_cast<short8*>(hiT + o) = hv;
        if (loT) *reinterpret_cast<short8*>(loT + o) = lv;
    }
}

// ---------------- LayerNorm: f32 [rows][1024] -> bf16 hi (+optional lo) ----------
__global__ __launch_bounds__(256)
void ln_k(const float* __restrict__ x, const float* __restrict__ g,
          const float* __restrict__ be, short* __restrict__ outhi,
          short* __restrict__ outlo)
{
    int row = blockIdx.x;
    const float* xr = x + (size_t)row * 1024;
    int tid = threadIdx.x;
    float4 v = reinterpret_cast<const float4*>(xr)[tid];
    float s = v.x + v.y + v.z + v.w;
    float q = v.x*v.x + v.y*v.y + v.z*v.z + v.w*v.w;
#pragma unroll
    for (int m = 1; m < 64; m <<= 1) { s += __shfl_xor(s, m); q += __shfl_xor(q, m); }
    __shared__ float ss[4], sq[4];
    int wid = tid >> 6;
    if ((tid & 63) == 0) { ss[wid] = s; sq[wid] = q; }
    __syncthreads();
    float S = ss[0] + ss[1] + ss[2] + ss[3];
    float Qs = sq[0] + sq[1] + sq[2] + sq[3];
    float mean = S * (1.f/1024.f);
    float var = Qs * (1.f/1024.f) - mean*mean;
    float rstd = rsqrtf(var + 1e-5f);
    float4 gv = reinterpret_cast<const float4*>(g)[tid];
    float4 bv = reinterpret_cast<const float4*>(be)[tid];
    float o[4];
    o[0] = (v.x-mean)*rstd*gv.x + bv.x;
    o[1] = (v.y-mean)*rstd*gv.y + bv.y;
    o[2] = (v.z-mean)*rstd*gv.z + bv.z;
    o[3] = (v.w-mean)*rstd*gv.w + bv.w;
    short hs[4], ls[4];
#pragma unroll
    for (int i = 0; i < 4; i++) split2(o[i], hs[i], ls[i]);
    typedef __attribute__((ext_vector_type(4))) short short4v;
    short4v hv; hv[0]=hs[0]; hv[1]=hs[1]; hv[2]=hs[2]; hv[3]=hs[3];
    *reinterpret_cast<short4v*>(outhi + (size_t)row*1024 + tid*4) = hv;
    if (outlo) {
        short4v lv; lv[0]=ls[0]; lv[1]=ls[1]; lv[2]=ls[2]; lv[3]=ls[3];
        *reinterpret_cast<short4v*>(outlo + (size_t)row*1024 + tid*4) = lv;
    }
}

// ---------------- cap projection ----------
__global__ __launch_bounds__(256)
void cap_k(const float* __restrict__ ts, const float* __restrict__ cw,
           const float* __restrict__ cb, float* __restrict__ capo)
{
    int b = blockIdx.y;
    int d = blockIdx.x * 64 + (threadIdx.x & 63);
    int ks = threadIdx.x >> 6;
    const float* t = ts + (size_t)b * 1024;
    float acc = 0.f;
    for (int k = ks*256; k < ks*256 + 256; k++)
        acc = fmaf(t[k], cw[(size_t)k*1024 + d], acc);
    __shared__ float red[4][64];
    red[ks][threadIdx.x & 63] = acc;
    __syncthreads();
    if (ks == 0)
        capo[(size_t)b*1024 + d] = red[0][threadIdx.x&63] + red[1][threadIdx.x&63]
                                 + red[2][threadIdx.x&63] + red[3][threadIdx.x&63] + cb[d];
}

// ---------------- gate: inline f32 LN2 + logits, top-2, softmax weights, lists ----
__global__ __launch_bounds__(64)
void gate_k(const float* __restrict__ x2, const float* __restrict__ g,
            const float* __restrict__ be, const float* __restrict__ capo,
            const float* __restrict__ gw, const float* __restrict__ gb,
            int* __restrict__ elist, float* __restrict__ ewt, int* __restrict__ cnt)
{
    int t = blockIdx.x;
    int b = t >> 10;
    int lane = threadIdx.x;
    const float* xr = x2 + (size_t)t * 1024;
    float v[16];
    float s = 0.f, q = 0.f;
#pragma unroll
    for (int i = 0; i < 16; i++) {
        v[i] = xr[i*64 + lane];
        s += v[i]; q += v[i]*v[i];
    }
#pragma unroll
    for (int m = 1; m < 64; m <<= 1) { s += __shfl_xor(s, m); q += __shfl_xor(q, m); }
    float mean = s * (1.f/1024.f);
    float var = q * (1.f/1024.f) - mean*mean;
    float rstd = rsqrtf(var + 1e-5f);
    float acc[8] = {0,0,0,0,0,0,0,0};
    const float* cr = capo + (size_t)b * 1024;
#pragma unroll
    for (int i = 0; i < 16; i++) {
        int d = i*64 + lane;
        float gi = (v[i]-mean)*rstd*g[d] + be[d] + cr[d];
        const float4* gp = reinterpret_cast<const float4*>(gw + (size_t)d*8);
        float4 g0 = gp[0], g1 = gp[1];
        acc[0] += gi*g0.x; acc[1] += gi*g0.y; acc[2] += gi*g0.z; acc[3] += gi*g0.w;
        acc[4] += gi*g1.x; acc[5] += gi*g1.y; acc[6] += gi*g1.z; acc[7] += gi*g1.w;
    }
#pragma unroll
    for (int e = 0; e < 8; e++)
#pragma unroll
        for (int m = 1; m < 64; m <<= 1) acc[e] += __shfl_xor(acc[e], m);
    if (lane == 0) {
        float v0 = -1e30f, v1 = -1e30f; int i0 = 0, i1 = 0;
#pragma unroll
        for (int e = 0; e < 8; e++) {
            float lg = acc[e] + gb[e];
            if (lg > v0) { v1 = v0; i1 = i0; v0 = lg; i0 = e; }
            else if (lg > v1) { v1 = lg; i1 = e; }
        }
        float w0 = 1.f / (1.f + __expf(v1 - v0));
        float w1 = 1.f - w0;
        int p0 = atomicAdd(&cnt[i0], 1);
        elist[i0*4096 + p0] = t; ewt[i0*4096 + p0] = w0;
        int p1 = atomicAdd(&cnt[i1], 1);
        elist[i1*4096 + p1] = t; ewt[i1*4096 + p1] = w1;
    }
}

// ---------------- scan: expert bases + load output ----------
__global__ void scan_k(const int* __restrict__ cnt, int* __restrict__ ebase,
                       float* __restrict__ outload)
{
    int t = threadIdx.x;
    if (t == 0) { int s = 0; for (int e = 0; e < 8; e++) { ebase[e] = s; s += cnt[e]; } }
    if (t < 8) outload[t] = (float)cnt[t] * (1.f/8192.f);
}

// ---------------- GEMM body: C = A[M,K] @ Bt[N,K]^T; m97 structure ----------------
// single-buffered LDS, global_load_lds x16B, XOR-swizzled chunks, 2 barriers/K-step.
// SP = split-bf16 3-term (hh + hl + lh). Tiles 128x128, BK=32.
enum { M_QKV = 0, M_WO = 1, M_F1 = 2, M_F2 = 3 };

template<int MODE, bool SP>
__device__ __forceinline__
void gemm_body(const short* __restrict__ Ahi, const short* __restrict__ Alo,
               const short* __restrict__ Bhi, const short* __restrict__ Blo,
               const float* __restrict__ bias,
               float* __restrict__ outf, short* __restrict__ outhi,
               const float* __restrict__ resid,
               const int* __restrict__ elist, const float* __restrict__ ew,
               const int* __restrict__ cnt, const int* __restrict__ ebase,
               int M, int N, int K)
{
    constexpr int NT = SP ? 4 : 2;       // tiles per K-step
    constexpr int IPW = NT * 2;          // staging issues per wave (NT*8/4 waves)
    constexpr bool MOE = (MODE == M_F1 || MODE == M_F2);
    int e = blockIdx.z;
    int m0 = blockIdx.y * 128, n0 = blockIdx.x * 128;
    int Mloc = M;
    int baseE = 0;
    if (MOE) {
        Mloc = cnt[e];
        if (m0 >= Mloc) return;
        baseE = ebase[e];
        Bhi += (size_t)e * 4194304;      // N*K == 4096*1024 for both FFN gemms
        bias += (size_t)e * N;
    }
    __shared__ short lds[NT * 4096];     // NT tiles x 8KB, single buffer
    int* rowmap = nullptr;
    if constexpr (MOE) {
        __shared__ int rowmap_s[128];
        rowmap = rowmap_s;
    }
    int tid = threadIdx.x;
    int lane = tid & 63, wid = tid >> 6;
    int wr = wid >> 1, wc = wid & 1;
    int rl = lane & 15, rg = lane >> 4;

    if constexpr (MOE) {
        if (tid < 128) {
            int mrow = m0 + tid;
            int ar;
            if (MODE == M_F1) {
                int idx = mrow < Mloc ? mrow : Mloc - 1;
                ar = elist[e*4096 + idx];
            } else {
                ar = baseE + mrow;
                if (ar > 8191) ar = 8191;
            }
            rowmap[tid] = ar;
        }
        __syncthreads();
    }

    // per-lane source pointers, computed once; chunk swizzle is row-independent
    int sch = (lane & 3) ^ ((lane >> 3) & 3);
    const short* src[IPW];
#pragma unroll
    for (int j = 0; j < IPW; j++) {
        int g = wid * IPW + j;           // global issue id, wave-uniform
        int tile = g >> 3, iss = g & 7;
        int row = iss*16 + (lane >> 2);
        const short* base;
        size_t ar;
        if (tile < (SP ? 2 : 1)) {
            ar = MOE ? (size_t)rowmap[row] : (size_t)(m0 + row);
            base = (SP && tile == 1) ? Alo : Ahi;
        } else {
            ar = (size_t)(n0 + row);
            base = (SP && tile == 3) ? Blo : Bhi;
        }
        src[j] = base + ar * (size_t)K + sch*8;
    }

    f32x4 acc[4][4] = {};
    int nt = K >> 5;
    for (int t = 0; t < nt; ++t) {
#pragma unroll
        for (int j = 0; j < IPW; j++) {
            cp16(lds + (wid*IPW + j)*512, src[j]);
            src[j] += 32;
        }
        __syncthreads();                 // vmcnt(0) drain + barrier: tile ready
        short8 afh[4], bfh[4], afl[4], bfl[4];
#pragma unroll
        for (int i = 0; i < 4; i++) {
            int ra = wr*64 + i*16 + rl;
            int ca = ra*32 + ((rg ^ ((rl >> 1) & 3)) * 8);
            afh[i] = *reinterpret_cast<const short8*>(lds + ca);
            if (SP) afl[i] = *reinterpret_cast<const short8*>(lds + 4096 + ca);
            int rb = wc*64 + i*16 + rl;
            int cb2 = rb*32 + ((rg ^ ((rl >> 1) & 3)) * 8);
            bfh[i] = *reinterpret_cast<const short8*>(lds + (SP?2:1)*4096 + cb2);
            if (SP) bfl[i] = *reinterpret_cast<const short8*>(lds + 3*4096 + cb2);
        }
#pragma unroll
        for (int mi = 0; mi < 4; mi++)
#pragma unroll
            for (int ni = 0; ni < 4; ni++) {
                acc[mi][ni] = MFMA16(afh[mi], bfh[ni], acc[mi][ni]);
                if (SP) {
                    acc[mi][ni] = MFMA16(afh[mi], bfl[ni], acc[mi][ni]);
                    acc[mi][ni] = MFMA16(afl[mi], bfh[ni], acc[mi][ni]);
                }
            }
        __syncthreads();                 // all reads done before next overwrite
    }
#pragma unroll
    for (int mi = 0; mi < 4; mi++) {
#pragma unroll
        for (int ni = 0; ni < 4; ni++) {
            int col = n0 + wc*64 + ni*16 + rl;
            f32x4 a = acc[mi][ni];
#pragma unroll
            for (int r = 0; r < 4; r++) {
                int mrow = m0 + wr*64 + mi*16 + rg*4 + r;
                if (mrow >= Mloc) continue;
                float val = a[r] + bias[col];
                if (MODE == M_QKV) {
                    int which = col >> 10, d = col & 1023;
                    int hh = d >> 6, hd = d & 63;
                    int bb = mrow >> 10, sidx = mrow & 1023;
                    size_t o = (size_t)which*4194304 + (((size_t)(bb*16 + hh))*1024 + sidx)*64 + hd;
                    short h, l; split2(val, h, l);
                    outhi[o] = h; outhi[12582912 + o] = l;
                } else if (MODE == M_WO) {
                    size_t o = (size_t)mrow*1024 + col;
                    outf[o] = val + resid[o];
                } else if (MODE == M_F1) {
                    float xx = val;
                    float z = 0.7978845608028654f * (xx + 0.044715f*xx*xx*xx);
                    float th = 1.f - 2.f/(1.f + __expf(2.f*z));
                    float gl = 0.5f*xx*(1.f + th);
                    outhi[(size_t)(baseE + mrow)*4096 + col] = f2b(gl);
                } else { // M_F2
                    int tok = elist[e*4096 + mrow];
                    float w = ew[e*4096 + mrow];
                    atomicAdd(&outf[(size_t)tok*1024 + col], w*val);
                }
            }
        }
    }
}

#define GEMM_ARGS const short* Ahi, const short* Alo, const short* Bhi, const short* Blo, \
    const float* bias, float* outf, short* outhi, const float* resid, \
    const int* elist, const float* ew, const int* cnt, const int* ebase, int M, int N, int K
#define GEMM_PASS Ahi, Alo, Bhi, Blo, bias, outf, outhi, resid, elist, ew, cnt, ebase, M, N, K

__global__ __launch_bounds__(256) void gemmQKV_k(GEMM_ARGS){ gemm_body<M_QKV,true >(GEMM_PASS); }
__global__ __launch_bounds__(256) void gemmWO_k (GEMM_ARGS){ gemm_body<M_WO, true >(GEMM_PASS); }
__global__ __launch_bounds__(256) void gemmF1_k (GEMM_ARGS){ gemm_body<M_F1, false>(GEMM_PASS); }
__global__ __launch_bounds__(256) void gemmF2_k (GEMM_ARGS){ gemm_body<M_F2, false>(GEMM_PASS); }

// ---------------- fused flash attention, split-bf16 (6-term QK, 3-term PV) ----
// grid: (qt=16, bh=64); block 256 (4 waves, 16 q-rows each); KV tiles of 64
__global__ __launch_bounds__(256)
void attn_k(const short* __restrict__ qkvhi, const short* __restrict__ qkvlo,
            const float* __restrict__ relb,
            short* __restrict__ obhi, short* __restrict__ oblo)
{
    int bh = blockIdx.y, qt = blockIdx.x;
    int b = bh >> 4, h = bh & 15;
    int tid = threadIdx.x, wid = tid >> 6, lane = tid & 63;
    int rl = lane & 15, rg = lane >> 4;
    const short* Qh = qkvhi + (size_t)bh * 65536;
    const short* Ql = qkvlo + (size_t)bh * 65536;
    const short* Kh_g = qkvhi + 4194304 + (size_t)bh * 65536;
    const short* Kl_g = qkvlo + 4194304 + (size_t)bh * 65536;
    const short* Vh_g = qkvhi + 8388608 + (size_t)bh * 65536;
    const short* Vl_g = qkvlo + 8388608 + (size_t)bh * 65536;
    __shared__ short Kh[64][72], Kl[64][72];
    __shared__ short Vh[64][72], Vl[64][72];
    __shared__ short Ph[4][16][72], Pl[4][16][72];
    int q0 = qt*64 + wid*16;
    short8 qh0 = *reinterpret_cast<const short8*>(Qh + (size_t)(q0+rl)*64 + rg*8);
    short8 qh1 = *reinterpret_cast<const short8*>(Qh + (size_t)(q0+rl)*64 + 32 + rg*8);
    short8 ql0 = *reinterpret_cast<const short8*>(Ql + (size_t)(q0+rl)*64 + rg*8);
    short8 ql1 = *reinterpret_cast<const short8*>(Ql + (size_t)(q0+rl)*64 + 32 + rg*8);
    f32x4 O[4] = {};
    float mr[4] = {-1e30f,-1e30f,-1e30f,-1e30f};
    float lr[4] = {0.f,0.f,0.f,0.f};
    const float* rb = relb + h*2047 + 1023;
    for (int kt = 0; kt < 16; ++kt) {
        int kb0 = kt * 64;
        __syncthreads();
#pragma unroll
        for (int j = 0; j < 2; j++) {
            int idx = j*256 + tid;
            int row = idx >> 3, cb = (idx & 7) * 8;
            *reinterpret_cast<short8*>(&Kh[row][cb]) =
                *reinterpret_cast<const short8*>(Kh_g + (size_t)(kb0+row)*64 + cb);
            *reinterpret_cast<short8*>(&Kl[row][cb]) =
                *reinterpret_cast<const short8*>(Kl_g + (size_t)(kb0+row)*64 + cb);
            short8 vh = *reinterpret_cast<const short8*>(Vh_g + (size_t)(kb0+row)*64 + cb);
            short8 vl = *reinterpret_cast<const short8*>(Vl_g + (size_t)(kb0+row)*64 + cb);
#pragma unroll
            for (int i = 0; i < 8; i++) { Vh[cb+i][row] = vh[i]; Vl[cb+i][row] = vl[i]; }
        }
        __syncthreads();
        f32x4 sc[4];
#pragma unroll
        for (int c = 0; c < 4; c++) {
            short8 kh0 = *reinterpret_cast<short8*>(&Kh[c*16+rl][rg*8]);
            short8 kh1 = *reinterpret_cast<short8*>(&Kh[c*16+rl][32+rg*8]);
            short8 kl0 = *reinterpret_cast<short8*>(&Kl[c*16+rl][rg*8]);
            short8 kl1 = *reinterpret_cast<short8*>(&Kl[c*16+rl][32+rg*8]);
            f32x4 t = {};
            t = MFMA16(qh0, kh0, t); t = MFMA16(qh1, kh1, t);
            t = MFMA16(qh0, kl0, t); t = MFMA16(qh1, kl1, t);
            t = MFMA16(ql0, kh0, t); t = MFMA16(ql1, kh1, t);
            sc[c] = t;
        }
        float pm[4] = {-1e30f,-1e30f,-1e30f,-1e30f};
#pragma unroll
        for (int c = 0; c < 4; c++) {
            int kk = kb0 + c*16 + rl;
#pragma unroll
            for (int r = 0; r < 4; r++) {
                int q = q0 + rg*4 + r;
                float sv = sc[c][r]*0.125f + rb[q - kk];
                sc[c][r] = sv;
                pm[r] = fmaxf(pm[r], sv);
            }
        }
#pragma unroll
        for (int r = 0; r < 4; r++) {
            pm[r] = fmaxf(pm[r], __shfl_xor(pm[r], 1));
            pm[r] = fmaxf(pm[r], __shfl_xor(pm[r], 2));
            pm[r] = fmaxf(pm[r], __shfl_xor(pm[r], 4));
            pm[r] = fmaxf(pm[r], __shfl_xor(pm[r], 8));
        }
        float scl[4], ps[4];
#pragma unroll
        for (int r = 0; r < 4; r++) {
            float mn = fmaxf(mr[r], pm[r]);
            scl[r] = __expf(mr[r] - mn);
            mr[r] = mn;
            ps[r] = 0.f;
        }
#pragma unroll
        for (int c = 0; c < 4; c++)
#pragma unroll
            for (int r = 0; r < 4; r++) {
                float p = __expf(sc[c][r] - mr[r]);
                sc[c][r] = p;
                ps[r] += p;
            }
#pragma unroll
        for (int r = 0; r < 4; r++) {
            ps[r] += __shfl_xor(ps[r], 1);
            ps[r] += __shfl_xor(ps[r], 2);
            ps[r] += __shfl_xor(ps[r], 4);
            ps[r] += __shfl_xor(ps[r], 8);
            lr[r] = lr[r]*scl[r] + ps[r];
        }
#pragma unroll
        for (int cc = 0; cc < 4; cc++) {
            O[cc][0] *= scl[0]; O[cc][1] *= scl[1];
            O[cc][2] *= scl[2]; O[cc][3] *= scl[3];
        }
#pragma unroll
        for (int c = 0; c < 4; c++)
#pragma unroll
            for (int r = 0; r < 4; r++) {
                short hp, lp; split2(sc[c][r], hp, lp);
                Ph[wid][rg*4+r][c*16+rl] = hp;
                Pl[wid][rg*4+r][c*16+rl] = lp;
            }
#pragma unroll
        for (int cc = 0; cc < 4; cc++) {
#pragma unroll
            for (int ks = 0; ks < 2; ks++) {
                short8 ph = *reinterpret_cast<short8*>(&Ph[wid][rl][ks*32 + rg*8]);
                short8 pl = *reinterpret_cast<short8*>(&Pl[wid][rl][ks*32 + rg*8]);
                short8 vh = *reinterpret_cast<short8*>(&Vh[cc*16+rl][ks*32 + rg*8]);
                short8 vl = *reinterpret_cast<short8*>(&Vl[cc*16+rl][ks*32 + rg*8]);
                O[cc] = MFMA16(ph, vh, O[cc]);
                O[cc] = MFMA16(ph, vl, O[cc]);
                O[cc] = MFMA16(pl, vh, O[cc]);
            }
        }
    }
#pragma unroll
    for (int cc = 0; cc < 4; cc++) {
#pragma unroll
        for (int r = 0; r < 4; r++) {
            int q = q0 + rg*4 + r;
            float val = O[cc][r] / lr[r];
            size_t o = ((size_t)(b*1024 + q))*1024 + h*64 + cc*16 + rl;
            short hv, lv; split2(val, hv, lv);
            obhi[o] = hv; oblo[o] = lv;
        }
    }
}

// ---------------------------------------------------------------------------
extern "C" void kernel_launch(void* const* d_in, const int* in_sizes, int n_in,
                              void* d_out, int out_size, void* d_ws, size_t ws_size,
                              hipStream_t stream)
{
    const float* x     = (const float*)d_in[0];
    const float* ts    = (const float*)d_in[1];
    const float* ln1g  = (const float*)d_in[2];
    const float* ln1b_ = (const float*)d_in[3];
    const float* wqkv  = (const float*)d_in[4];
    const float* bqkv  = (const float*)d_in[5];
    const float* wo    = (const float*)d_in[6];
    const float* bo    = (const float*)d_in[7];
    const float* relb  = (const float*)d_in[8];
    const float* ln2g  = (const float*)d_in[9];
    const float* ln2b_ = (const float*)d_in[10];
    const float* capw  = (const float*)d_in[11];
    const float* capb  = (const float*)d_in[12];
    const float* gatew = (const float*)d_in[13];
    const float* gateb = (const float*)d_in[14];
    const float* w1    = (const float*)d_in[15];
    const float* b1    = (const float*)d_in[16];
    const float* w2    = (const float*)d_in[17];
    const float* b2    = (const float*)d_in[18];
    float* out = (float*)d_out;

    char* p = (char*)d_ws;
    short* w1T    = (short*)p; p += 67108864;
    short* w2T    = (short*)p; p += 67108864;
    short* wqThi  = (short*)p; p += 6291456;
    short* wqTlo  = (short*)p; p += 6291456;
    short* woThi  = (short*)p; p += 2097152;
    short* woTlo  = (short*)p; p += 2097152;
    short* qkvhi  = (short*)p; p += 50331648;   // hi plane [0,12.5M) + lo plane [12.5M,25M) elems
    short* qkvlo  = qkvhi + 12582912;
    short* h2b    = (short*)p; p += 8388608;
    float* capo   = (float*)p; p += 16384;
    int*   elist  = (int*)p;   p += 131072;
    float* ewt    = (float*)p; p += 131072;
    int*   cnt    = (int*)p;   p += 256;
    int*   ebase  = (int*)p;   p += 256;
    short* mid    = (short*)p; p += 67108864;   // 8192x4096 bf16; front aliased below
    short* h1hi   = mid;                        // live: ln1 -> QKV gemm
    short* h1lo   = mid + 4194304;
    short* obhi   = mid + 8388608;              // live: attn -> WO gemm
    short* oblo   = mid + 12582912;

    hipMemsetAsync(cnt, 0, 32, stream);

    castT_k<<<dim3(48, 16, 1), 256, 0, stream>>>(wqkv, wqThi, wqTlo, 1024, 3072);
    castT_k<<<dim3(16, 16, 1), 256, 0, stream>>>(wo,   woThi, woTlo, 1024, 1024);
    castT_k<<<dim3(64, 16, 8), 256, 0, stream>>>(w1,   w1T,  nullptr, 1024, 4096);
    castT_k<<<dim3(16, 64, 8), 256, 0, stream>>>(w2,   w2T,  nullptr, 4096, 1024);

    ln_k<<<4096, 256, 0, stream>>>(x, ln1g, ln1b_, h1hi, h1lo);

    gemmQKV_k<<<dim3(24, 32, 1), 256, 0, stream>>>(
        h1hi, h1lo, wqThi, wqTlo, bqkv, nullptr, qkvhi,
        nullptr, nullptr, nullptr, nullptr, nullptr, 4096, 3072, 1024);

    attn_k<<<dim3(16, 64), 256, 0, stream>>>(qkvhi, qkvlo, relb, obhi, oblo);

    gemmWO_k<<<dim3(8, 32, 1), 256, 0, stream>>>(
        obhi, oblo, woThi, woTlo, bo, out, nullptr,
        x, nullptr, nullptr, nullptr, nullptr, 4096, 1024, 1024);

    cap_k<<<dim3(16, 4), 256, 0, stream>>>(ts, capw, capb, capo);

    ln_k<<<4096, 256, 0, stream>>>(out, ln2g, ln2b_, h2b, nullptr);

    gate_k<<<4096, 64, 0, stream>>>(out, ln2g, ln2b_, capo, gatew, gateb,
                                    elist, ewt, cnt);

    scan_k<<<1, 64, 0, stream>>>(cnt, ebase, out + 4194304);

    gemmF1_k<<<dim3(32, 32, 8), 256, 0, stream>>>(
        h2b, nullptr, w1T, nullptr, b1, nullptr, mid,
        nullptr, elist, ewt, cnt, ebase, 4096, 4096, 1024);

    gemmF2_k<<<dim3(8, 32, 8), 256, 0, stream>>>(
        mid, nullptr, w2T, nullptr, b2, out, nullptr,
        nullptr, elist, ewt, cnt, ebase, 4096, 1024, 4096);

    (void)in_sizes; (void)n_in; (void)out_size; (void)ws_size;
}